// Round 4
// baseline (751.197 us; speedup 1.0000x reference)
//
#include <hip/hip_runtime.h>
#include <hip/hip_bf16.h>

typedef __attribute__((ext_vector_type(8))) short bf16x8;
typedef __attribute__((ext_vector_type(4))) float f32x4;
typedef __attribute__((address_space(3))) unsigned int lds_u32;
typedef __attribute__((address_space(1))) const unsigned int glb_u32;

#define LOG2_10000 13.287712379549449f
#define QSCALE (0.07216878364870323f * 1.4426950408889634f)  // 192^-0.5 * log2(e)

static __device__ __forceinline__ unsigned short f2bf(float f) {
  union { float f; unsigned int u; } v; v.f = f;
  unsigned int r = v.u + 0x7FFFu + ((v.u >> 16) & 1u);
  return (unsigned short)(r >> 16);
}
static __device__ __forceinline__ float bf2f(unsigned short h) {
  union { unsigned int u; float f; } v; v.u = ((unsigned int)h) << 16;
  return v.f;
}
static __device__ __forceinline__ f32x4 mfma16(bf16x8 a, bf16x8 b, f32x4 c) {
  return __builtin_amdgcn_mfma_f32_16x16x32_bf16(a, b, c, 0, 0, 0);
}
static __device__ __forceinline__ void gl_lds16(const void* g, void* l) {
  __builtin_amdgcn_global_load_lds((glb_u32*)g, (lds_u32*)l, 16, 0, 0);
}

// ---------- cast f32 -> bf16 with trailing zero-fill (pad region) ----------
__global__ __launch_bounds__(256) void cast_bf16(const float* __restrict__ src,
                                                 unsigned short* __restrict__ dst,
                                                 int nsrc, int ndst) {
  int i = (blockIdx.x * 256 + threadIdx.x) * 4;
  if (i >= ndst) return;
  float4 v = make_float4(0.f, 0.f, 0.f, 0.f);
  if (i < nsrc) v = *(const float4*)(src + i);
  uint2 o;
  o.x = (unsigned int)f2bf(v.x) | ((unsigned int)f2bf(v.y) << 16);
  o.y = (unsigned int)f2bf(v.z) | ((unsigned int)f2bf(v.w) << 16);
  *(uint2*)(dst + i) = o;
}

// ---------- bf16 NT GEMM: C[M,N] = alpha * A[M,K] * Bt[N,K]^T ----------
template <bool OUTBF>
__global__ __launch_bounds__(256, 2) void gemm_bf16(const unsigned short* __restrict__ A,
                                                    const unsigned short* __restrict__ Bt,
                                                    void* __restrict__ Cv,
                                                    int M, int N, int K, float alpha) {
  __shared__ unsigned short As[128 * 32];
  __shared__ unsigned short Bs[128 * 32];
  const int tid = threadIdx.x;
  const int w = tid >> 6, lane = tid & 63;
  const int quad = lane >> 4, l15 = lane & 15;
  const int wx = w & 1, wy = w >> 1;
  const int bm = blockIdx.y * 128, bn = blockIdx.x * 128;

  f32x4 acc[4][4];
#pragma unroll
  for (int i = 0; i < 4; ++i)
#pragma unroll
    for (int j = 0; j < 4; ++j) { acc[i][j][0] = 0.f; acc[i][j][1] = 0.f; acc[i][j][2] = 0.f; acc[i][j][3] = 0.f; }

  const int lrow = lane >> 2;
  const int lcol = (lane & 3) * 8;
  const unsigned short* Ag = A + (size_t)(bm + w * 16 + lrow) * K + lcol;
  const unsigned short* Bg = Bt + (size_t)(bn + w * 16 + lrow) * K + lcol;
  unsigned short* AsB = &As[(w * 16) * 32];
  unsigned short* BsB = &Bs[(w * 16) * 32];

  for (int k0 = 0; k0 < K; k0 += 32) {
    __syncthreads();
    gl_lds16(Ag + k0, AsB);
    gl_lds16(Ag + (size_t)64 * K + k0, AsB + 64 * 32);
    gl_lds16(Bg + k0, BsB);
    gl_lds16(Bg + (size_t)64 * K + k0, BsB + 64 * 32);
    __syncthreads();
    bf16x8 aF[4], bF[4];
#pragma unroll
    for (int i = 0; i < 4; ++i)
      aF[i] = *(const bf16x8*)&As[(wy * 64 + i * 16 + l15) * 32 + quad * 8];
#pragma unroll
    for (int j = 0; j < 4; ++j)
      bF[j] = *(const bf16x8*)&Bs[(wx * 64 + j * 16 + l15) * 32 + quad * 8];
#pragma unroll
    for (int i = 0; i < 4; ++i)
#pragma unroll
      for (int j = 0; j < 4; ++j)
        acc[i][j] = mfma16(aF[i], bF[j], acc[i][j]);
  }

#pragma unroll
  for (int i = 0; i < 4; ++i)
#pragma unroll
    for (int r = 0; r < 4; ++r) {
      const size_t row = (size_t)(bm + wy * 64 + i * 16 + quad * 4 + r) * (size_t)N;
#pragma unroll
      for (int j = 0; j < 4; ++j) {
        const int col = bn + wx * 64 + j * 16 + l15;
        if (OUTBF) ((unsigned short*)Cv)[row + col] = f2bf(acc[i][j][r] * alpha);
        else       ((float*)Cv)[row + col] = acc[i][j][r];
      }
    }
}

// ---------- RoPE on q_pe, in place on bf16 q ----------
__global__ __launch_bounds__(256) void rope_q_bf(unsigned short* __restrict__ qh) {
  int idx = blockIdx.x * 256 + threadIdx.x;
  int j = idx & 31;
  int th = idx >> 5;
  int h = th & 15;
  int t = th >> 4;
  float fr = exp2f(-(float)j * (LOG2_10000 / 32.f));
  float ang = (float)t * fr;
  float sn, cs;
  sincosf(ang, &sn, &cs);
  unsigned short* p = qh + (size_t)t * 3072 + h * 192 + 128 + 2 * j;
  unsigned int v = *(unsigned int*)p;
  float a = bf2f((unsigned short)v), b = bf2f((unsigned short)(v >> 16));
  float na = a * cs - b * sn, nb = a * sn + b * cs;
  *(unsigned int*)p = (unsigned int)f2bf(na) | ((unsigned int)f2bf(nb) << 16);
}

// ---------- LayerNorm(kv) + RoPE(k_pe); f32 in (stride 640), bf16 out ----------
__global__ __launch_bounds__(256) void ln_rope_k(const float* __restrict__ kvfull,
                                                 const float* __restrict__ gamma,
                                                 const float* __restrict__ beta,
                                                 unsigned short* __restrict__ kvln,
                                                 unsigned short* __restrict__ kpe) {
  const int t = blockIdx.x;
  const int tid = threadIdx.x;
  const float* row = kvfull + (size_t)t * 640;
  float x0 = row[tid], x1 = row[tid + 256];
  float sm = x0 + x1;
  float sq = x0 * x0 + x1 * x1;
#pragma unroll
  for (int off = 1; off < 64; off <<= 1) {
    sm += __shfl_xor(sm, off, 64);
    sq += __shfl_xor(sq, off, 64);
  }
  __shared__ float rs[4], rq[4];
  const int lane = tid & 63, wid = tid >> 6;
  if (lane == 0) { rs[wid] = sm; rq[wid] = sq; }
  __syncthreads();
  float tsm = rs[0] + rs[1] + rs[2] + rs[3];
  float tsq = rq[0] + rq[1] + rq[2] + rq[3];
  float mu = tsm * (1.f / 512.f);
  float var = tsq * (1.f / 512.f) - mu * mu;
  float inv = rsqrtf(var + 1e-5f);
  kvln[(size_t)t * 512 + tid]       = f2bf((x0 - mu) * inv * gamma[tid] + beta[tid]);
  kvln[(size_t)t * 512 + tid + 256] = f2bf((x1 - mu) * inv * gamma[tid + 256] + beta[tid + 256]);
  if (tid < 32) {
    float a = row[512 + 2 * tid], b = row[512 + 2 * tid + 1];
    float fr = exp2f(-(float)tid * (LOG2_10000 / 32.f));
    float ang = (float)t * fr;
    float sn, cs;
    sincosf(ang, &sn, &cs);
    kpe[(size_t)t * 64 + 2 * tid]     = f2bf(a * cs - b * sn);
    kpe[(size_t)t * 64 + 2 * tid + 1] = f2bf(a * sn + b * cs);
  }
}

// ---------- V transpose: kvb[t][h*256+128+c] -> Vt[h][c][t] ----------
__global__ __launch_bounds__(256) void transpose_v(const unsigned short* __restrict__ kvb,
                                                   unsigned short* __restrict__ Vt) {
  __shared__ unsigned short tile[64][72];
  const int tb = blockIdx.x * 64;
  const int h  = blockIdx.y >> 1;
  const int c0 = (blockIdx.y & 1) * 64;
  const int tid = threadIdx.x;
  const int r  = tid >> 4;
  const int c4 = (tid & 15) * 4;
#pragma unroll
  for (int rep = 0; rep < 4; ++rep) {
    const int t = rep * 16 + r;
    uint2 d = *(const uint2*)(kvb + (size_t)(tb + t) * 4096 + h * 256 + 128 + c0 + c4);
    *(uint2*)&tile[t][c4] = d;
  }
  __syncthreads();
#pragma unroll
  for (int rep = 0; rep < 4; ++rep) {
    const int c = rep * 16 + r;
    unsigned int lo = (unsigned int)tile[c4 + 0][c] | ((unsigned int)tile[c4 + 1][c] << 16);
    unsigned int hi = (unsigned int)tile[c4 + 2][c] | ((unsigned int)tile[c4 + 3][c] << 16);
    uint2 o; o.x = lo; o.y = hi;
    *(uint2*)(Vt + ((size_t)h * 128 + c0 + c) * 4096 + tb + c4) = o;
  }
}

// ---------- helper: stage one 64-key K panel set into an sK buffer ----------
static __device__ __forceinline__ void stage_k(const unsigned short* kvbh,
                                               const unsigned short* kpe,
                                               int k0, unsigned short* dst,
                                               int w, int lane) {
#pragma unroll
  for (int j = 0; j < 6; ++j) {
    const int i = w * 6 + j;
    const int granule = i * 64 + lane;
    const int g = granule >> 8;
    const int key = (granule >> 2) & 63;
    const int col = (g << 5) + ((granule & 3) << 3);
    const unsigned short* src = (col < 128)
        ? kvbh + (size_t)(k0 + key) * 4096 + col
        : kpe + (size_t)(k0 + key) * 64 + (col - 128);
    gl_lds16(src, dst + i * 512);
  }
}

// ---------- MFMA flash attention v5: K double-buffered (counted vmcnt), ----------
// V direct-to-registers from pre-transposed Vt (64B-coalesced), 4 waves x 32 rows.
// Pipeline per tile: [stage K(t+1) | load V(t) regs] -> vmcnt(counted)+barrier ->
// QK^T(t) -> lgkm+barrier -> softmax/pack/PV(t).  No vmcnt(0) drain in the loop.
__global__ __launch_bounds__(256, 2) void attn_mfma(const unsigned short* __restrict__ qh,
                                                    const unsigned short* __restrict__ kvb,
                                                    const unsigned short* __restrict__ kpe,
                                                    const unsigned short* __restrict__ Vt,
                                                    unsigned short* __restrict__ attnh) {
  __shared__ unsigned short sK[2][6 * 2048];  // 48 KB: dbuf x 6 panels [64 keys][32]
  __shared__ unsigned short sP[128 * 72];     // 18 KB: [m][k], per-wave row slices

  const int bid = blockIdx.x;
  const int h = bid & 15;
  const int z = bid >> 4;
  const int qt = (z < 16) ? (31 - z) : (z - 16);
  const int q0 = qt * 128;
  const int tid = threadIdx.x;
  const int w = tid >> 6, lane = tid & 63;
  const int quad = lane >> 4, l15 = lane & 15;
  const int wq0 = w * 32;

  const unsigned short* kvbh = kvb + h * 256;
  const unsigned short* Vth = Vt + (size_t)h * 128 * 4096;

  // Q fragments (B-operand: lane l15 = q-row m)
  bf16x8 qF[2][6];
#pragma unroll
  for (int i = 0; i < 2; ++i)
#pragma unroll
    for (int g = 0; g < 6; ++g) {
      const int grow = q0 + wq0 + i * 16 + l15;
      union { uint4 u; bf16x8 v; } tmp;
      tmp.u = *(const uint4*)(qh + (size_t)grow * 3072 + h * 192 + g * 32 + quad * 8);
      qF[i][g] = tmp.v;
    }

  f32x4 oA[2][8];
  float mi[2], li[2];   // per lane: row m = i*16 + l15 (replicated across quads)
#pragma unroll
  for (int i = 0; i < 2; ++i) {
    mi[i] = -1e30f; li[i] = 0.f;
#pragma unroll
    for (int j = 0; j < 8; ++j) { oA[i][j][0] = 0.f; oA[i][j][1] = 0.f; oA[i][j][2] = 0.f; oA[i][j][3] = 0.f; }
  }

  const int nk = 2 * (qt + 1);

  // prologue: stage K(0) into buffer 0 (drained by counted vmcnt at kt=0)
  stage_k(kvbh, kpe, 0, &sK[0][0], w, lane);

  for (int kt = 0; kt < nk; ++kt) {
    const int k0 = kt * 64;
    const int p = kt & 1;

    // ---- prefetch K(kt+1) into other buffer (async; stays in flight) ----
    if (kt + 1 < nk)
      stage_k(kvbh, kpe, k0 + 64, &sK[p ^ 1][0], w, lane);
    __asm__ __volatile__("" ::: "memory");   // pin issue order: K before V

    // ---- V(kt) direct to registers (16x dwordx4, 64B-coalesced lines) ----
    bf16x8 vr[2][8];
#pragma unroll
    for (int ks = 0; ks < 2; ++ks)
#pragma unroll
      for (int j = 0; j < 8; ++j) {
        union { uint4 u; bf16x8 v; } t;
        t.u = *(const uint4*)(Vth + (size_t)(j * 16 + l15) * 4096 + k0 + ks * 32 + quad * 8);
        vr[ks][j] = t.v;
      }

    // ---- counted wait: drain K(kt) only; keep K(kt+1)+V(kt) in flight ----
    if (kt + 1 < nk) { __asm__ __volatile__("s_waitcnt vmcnt(22)" ::: "memory"); }
    else             { __asm__ __volatile__("s_waitcnt vmcnt(16)" ::: "memory"); }
    __builtin_amdgcn_s_barrier();            // K(kt) visible to all waves
    __asm__ __volatile__("" ::: "memory");

    // ---- S^T = K Q^T: sc[kk][i], D row = key(quad*4+r), col = m(l15) ----
    const unsigned short* sKp = &sK[p][0];
    f32x4 sc[4][2];
#pragma unroll
    for (int kk = 0; kk < 4; ++kk)
#pragma unroll
      for (int i = 0; i < 2; ++i) { sc[kk][i][0] = 0.f; sc[kk][i][1] = 0.f; sc[kk][i][2] = 0.f; sc[kk][i][3] = 0.f; }
#pragma unroll
    for (int g = 0; g < 6; ++g) {
      bf16x8 kF[4];
#pragma unroll
      for (int kk = 0; kk < 4; ++kk)
        kF[kk] = *(const bf16x8*)&sKp[g * 2048 + (kk * 16 + l15) * 32 + quad * 8];
#pragma unroll
      for (int kk = 0; kk < 4; ++kk)
#pragma unroll
        for (int i = 0; i < 2; ++i)
          sc[kk][i] = mfma16(kF[kk], qF[i][g], sc[kk][i]);
    }

    // ---- release sK[p] for next iter's prefetch ----
    __asm__ __volatile__("s_waitcnt lgkmcnt(0)" ::: "memory");
    __builtin_amdgcn_s_barrier();
    __asm__ __volatile__("" ::: "memory");

    // ---- online softmax over keys (in-lane 16 + shfl_xor 16,32) ----
    const bool msk = (kt >= 2 * qt);
    float alpha[2];
#pragma unroll
    for (int i = 0; i < 2; ++i) {
      const int grow = q0 + wq0 + i * 16 + l15;
      if (msk) {
#pragma unroll
        for (int kk = 0; kk < 4; ++kk)
#pragma unroll
          for (int rr = 0; rr < 4; ++rr) {
            const int gk = k0 + kk * 16 + quad * 4 + rr;
            if (gk > grow) sc[kk][i][rr] = -1e30f;
          }
      }
      float mx = -1e30f;
#pragma unroll
      for (int kk = 0; kk < 4; ++kk)
#pragma unroll
        for (int rr = 0; rr < 4; ++rr) mx = fmaxf(mx, sc[kk][i][rr]);
      mx = fmaxf(mx, __shfl_xor(mx, 16, 64));
      mx = fmaxf(mx, __shfl_xor(mx, 32, 64));
      const float mnew = fmaxf(mi[i], mx);
      alpha[i] = __builtin_amdgcn_exp2f(mi[i] - mnew);
      float sum = 0.f;
#pragma unroll
      for (int kk = 0; kk < 4; ++kk)
#pragma unroll
        for (int rr = 0; rr < 4; ++rr) {
          const float pe = __builtin_amdgcn_exp2f(sc[kk][i][rr] - mnew);
          sc[kk][i][rr] = pe;
          sum += pe;
        }
      sum += __shfl_xor(sum, 16, 64);
      sum += __shfl_xor(sum, 32, 64);
      li[i] = li[i] * alpha[i] + sum;
      mi[i] = mnew;
    }

    // ---- rescale O (alpha fetched to C-layout rows: 8 shfls) ----
#pragma unroll
    for (int i = 0; i < 2; ++i)
#pragma unroll
      for (int rr = 0; rr < 4; ++rr) {
        const float af = __shfl(alpha[i], (lane & 48) | (quad * 4 + rr), 64);
#pragma unroll
        for (int j = 0; j < 8; ++j) oA[i][j][rr] *= af;
      }

    // ---- pack P (keys consecutive in regs) -> 8 b64 LDS writes ----
#pragma unroll
    for (int kk = 0; kk < 4; ++kk)
#pragma unroll
      for (int i = 0; i < 2; ++i) {
        union { float f; unsigned int u; } p0, p1, p2, p3;
        p0.f = sc[kk][i][0]; p1.f = sc[kk][i][1]; p2.f = sc[kk][i][2]; p3.f = sc[kk][i][3];
        uint2 pk;
        pk.x = (p0.u >> 16) | (p1.u & 0xFFFF0000u);
        pk.y = (p2.u >> 16) | (p3.u & 0xFFFF0000u);
        *(uint2*)&sP[(size_t)(wq0 + i * 16 + l15) * 72 + kk * 16 + quad * 4] = pk;
      }

    // ---- O += P V (own sP rows: no barrier; V from registers) ----
#pragma unroll
    for (int ks = 0; ks < 2; ++ks) {
      bf16x8 pF[2];
#pragma unroll
      for (int i = 0; i < 2; ++i)
        pF[i] = *(const bf16x8*)&sP[(size_t)(wq0 + i * 16 + l15) * 72 + ks * 32 + quad * 8];
#pragma unroll
      for (int i = 0; i < 2; ++i)
#pragma unroll
        for (int j = 0; j < 8; ++j)
          oA[i][j] = mfma16(pF[i], vr[ks][j], oA[i][j]);
    }
  }

  // ---- epilogue: O / l (l fetched to C-layout rows) ----
  float linv[2];
  linv[0] = 1.f / li[0];
  linv[1] = 1.f / li[1];
#pragma unroll
  for (int i = 0; i < 2; ++i)
#pragma unroll
    for (int rr = 0; rr < 4; ++rr) {
      const float lf = __shfl(linv[i], (lane & 48) | (quad * 4 + rr), 64);
      const size_t grow = (size_t)(q0 + wq0 + i * 16 + quad * 4 + rr);
#pragma unroll
      for (int j = 0; j < 8; ++j)
        attnh[grow * 2048 + h * 128 + j * 16 + l15] = f2bf(oA[i][j][rr] * lf);
    }
}

extern "C" void kernel_launch(void* const* d_in, const int* in_sizes, int n_in,
                              void* d_out, int out_size, void* d_ws, size_t ws_size,
                              hipStream_t stream) {
  const float* x        = (const float*)d_in[0];
  const float* wq       = (const float*)d_in[1];
  const float* wkv_a    = (const float*)d_in[2];
  const float* kv_gamma = (const float*)d_in[3];
  const float* kv_beta  = (const float*)d_in[4];
  const float* wkv_b    = (const float*)d_in[5];
  const float* wo       = (const float*)d_in[6];
  float* out = (float*)d_out;

  char* p = (char*)d_ws;
  unsigned short* xh    = (unsigned short*)p; p += (size_t)4096 * 2048 * 2;  // also Vt (aliased after xh dead)
  unsigned short* wqh   = (unsigned short*)p; p += (size_t)3072 * 2048 * 2;
  unsigned short* wah   = (unsigned short*)p; p += (size_t)640 * 2048 * 2;
  unsigned short* wbh   = (unsigned short*)p; p += (size_t)4096 * 512 * 2;
  unsigned short* woh   = (unsigned short*)p; p += (size_t)2048 * 2048 * 2;
  unsigned short* qh    = (unsigned short*)p; p += (size_t)4096 * 3072 * 2;
  float*          kvful = (float*)p;          p += (size_t)4096 * 640 * 4;
  unsigned short* kvlnh = (unsigned short*)p; p += (size_t)4096 * 512 * 2;
  unsigned short* kpeh  = (unsigned short*)p; p += (size_t)4096 * 64 * 2;
  unsigned short* kvbh  = (unsigned short*)p; p += (size_t)4096 * 4096 * 2;
  unsigned short* attnh = (unsigned short*)p; p += (size_t)4096 * 2048 * 2;
  if ((size_t)(p - (char*)d_ws) > ws_size) return;
  unsigned short* Vt = xh;  // 16 MB alias: xh consumed by gemms 1&3 before transpose_v runs

  cast_bf16<<<8192, 256, 0, stream>>>(x,     xh,  4096 * 2048, 4096 * 2048);
  cast_bf16<<<6144, 256, 0, stream>>>(wq,    wqh, 3072 * 2048, 3072 * 2048);
  cast_bf16<<<1280, 256, 0, stream>>>(wkv_a, wah, 576 * 2048,  640 * 2048);
  cast_bf16<<<2048, 256, 0, stream>>>(wkv_b, wbh, 4096 * 512,  4096 * 512);
  cast_bf16<<<4096, 256, 0, stream>>>(wo,    woh, 2048 * 2048, 2048 * 2048);

  // 1. q = QSCALE * (x @ wq^T) -> bf16 (exp2-domain attention)
  gemm_bf16<true><<<dim3(24, 32), 256, 0, stream>>>(xh, wqh, qh, 4096, 3072, 2048, QSCALE);
  // 2. rope(q_pe) in place
  rope_q_bf<<<8192, 256, 0, stream>>>(qh);
  // 3. kv_full = x @ wkv_a^T -> f32 (LN stats precision), padded N=640
  gemm_bf16<false><<<dim3(5, 32), 256, 0, stream>>>(xh, wah, kvful, 4096, 640, 2048, 1.f);
  // 4. layernorm + rope(k_pe) -> bf16
  ln_rope_k<<<4096, 256, 0, stream>>>(kvful, kv_gamma, kv_beta, kvlnh, kpeh);
  // 5. kvb = kvln @ wkv_b^T -> bf16
  gemm_bf16<true><<<dim3(32, 32), 256, 0, stream>>>(kvlnh, wbh, kvbh, 4096, 4096, 512, 1.f);
  // 5b. V^T for attention (overwrites xh — dead by now)
  transpose_v<<<dim3(64, 32), 256, 0, stream>>>(kvbh, Vt);
  // 6. causal MFMA flash attention (K-dbuf pipelined)
  attn_mfma<<<512, 256, 0, stream>>>(qh, kvbh, kpeh, Vt, attnh);
  // 7. out = attn @ wo^T -> f32
  gemm_bf16<false><<<dim3(16, 32), 256, 0, stream>>>(attnh, woh, out, 4096, 2048, 2048, 1.f);
}

// Round 5
// 485.288 us; speedup vs baseline: 1.5479x; 1.5479x over previous
//
#include <hip/hip_runtime.h>
#include <hip/hip_bf16.h>

typedef __attribute__((ext_vector_type(8))) short bf16x8;
typedef __attribute__((ext_vector_type(4))) float f32x4;
typedef __attribute__((address_space(3))) unsigned int lds_u32;
typedef __attribute__((address_space(1))) const unsigned int glb_u32;

#define LOG2_10000 13.287712379549449f
#define QSCALE (0.07216878364870323f * 1.4426950408889634f)  // 192^-0.5 * log2(e)

static __device__ __forceinline__ unsigned short f2bf(float f) {
  union { float f; unsigned int u; } v; v.f = f;
  unsigned int r = v.u + 0x7FFFu + ((v.u >> 16) & 1u);
  return (unsigned short)(r >> 16);
}
static __device__ __forceinline__ float bf2f(unsigned short h) {
  union { unsigned int u; float f; } v; v.u = ((unsigned int)h) << 16;
  return v.f;
}
static __device__ __forceinline__ f32x4 mfma16(bf16x8 a, bf16x8 b, f32x4 c) {
  return __builtin_amdgcn_mfma_f32_16x16x32_bf16(a, b, c, 0, 0, 0);
}
static __device__ __forceinline__ void gl_lds16(const void* g, void* l) {
  __builtin_amdgcn_global_load_lds((glb_u32*)g, (lds_u32*)l, 16, 0, 0);
}

// ---------- cast f32 -> bf16 with trailing zero-fill (pad region) ----------
__global__ __launch_bounds__(256) void cast_bf16(const float* __restrict__ src,
                                                 unsigned short* __restrict__ dst,
                                                 int nsrc, int ndst) {
  int i = (blockIdx.x * 256 + threadIdx.x) * 4;
  if (i >= ndst) return;
  float4 v = make_float4(0.f, 0.f, 0.f, 0.f);
  if (i < nsrc) v = *(const float4*)(src + i);
  uint2 o;
  o.x = (unsigned int)f2bf(v.x) | ((unsigned int)f2bf(v.y) << 16);
  o.y = (unsigned int)f2bf(v.z) | ((unsigned int)f2bf(v.w) << 16);
  *(uint2*)(dst + i) = o;
}

// ---------- bf16 NT GEMM: C[M,N] = alpha * A[M,K] * Bt[N,K]^T ----------
template <bool OUTBF>
__global__ __launch_bounds__(256, 2) void gemm_bf16(const unsigned short* __restrict__ A,
                                                    const unsigned short* __restrict__ Bt,
                                                    void* __restrict__ Cv,
                                                    int M, int N, int K, float alpha) {
  __shared__ unsigned short As[128 * 32];
  __shared__ unsigned short Bs[128 * 32];
  const int tid = threadIdx.x;
  const int w = tid >> 6, lane = tid & 63;
  const int quad = lane >> 4, l15 = lane & 15;
  const int wx = w & 1, wy = w >> 1;
  const int bm = blockIdx.y * 128, bn = blockIdx.x * 128;

  f32x4 acc[4][4];
#pragma unroll
  for (int i = 0; i < 4; ++i)
#pragma unroll
    for (int j = 0; j < 4; ++j) { acc[i][j][0] = 0.f; acc[i][j][1] = 0.f; acc[i][j][2] = 0.f; acc[i][j][3] = 0.f; }

  const int lrow = lane >> 2;
  const int lcol = (lane & 3) * 8;
  const unsigned short* Ag = A + (size_t)(bm + w * 16 + lrow) * K + lcol;
  const unsigned short* Bg = Bt + (size_t)(bn + w * 16 + lrow) * K + lcol;
  unsigned short* AsB = &As[(w * 16) * 32];
  unsigned short* BsB = &Bs[(w * 16) * 32];

  for (int k0 = 0; k0 < K; k0 += 32) {
    __syncthreads();
    gl_lds16(Ag + k0, AsB);
    gl_lds16(Ag + (size_t)64 * K + k0, AsB + 64 * 32);
    gl_lds16(Bg + k0, BsB);
    gl_lds16(Bg + (size_t)64 * K + k0, BsB + 64 * 32);
    __syncthreads();
    bf16x8 aF[4], bF[4];
#pragma unroll
    for (int i = 0; i < 4; ++i)
      aF[i] = *(const bf16x8*)&As[(wy * 64 + i * 16 + l15) * 32 + quad * 8];
#pragma unroll
    for (int j = 0; j < 4; ++j)
      bF[j] = *(const bf16x8*)&Bs[(wx * 64 + j * 16 + l15) * 32 + quad * 8];
#pragma unroll
    for (int i = 0; i < 4; ++i)
#pragma unroll
      for (int j = 0; j < 4; ++j)
        acc[i][j] = mfma16(aF[i], bF[j], acc[i][j]);
  }

#pragma unroll
  for (int i = 0; i < 4; ++i)
#pragma unroll
    for (int r = 0; r < 4; ++r) {
      const size_t row = (size_t)(bm + wy * 64 + i * 16 + quad * 4 + r) * (size_t)N;
#pragma unroll
      for (int j = 0; j < 4; ++j) {
        const int col = bn + wx * 64 + j * 16 + l15;
        if (OUTBF) ((unsigned short*)Cv)[row + col] = f2bf(acc[i][j][r] * alpha);
        else       ((float*)Cv)[row + col] = acc[i][j][r];
      }
    }
}

// ---------- RoPE on q_pe, in place on bf16 q ----------
__global__ __launch_bounds__(256) void rope_q_bf(unsigned short* __restrict__ qh) {
  int idx = blockIdx.x * 256 + threadIdx.x;
  int j = idx & 31;
  int th = idx >> 5;
  int h = th & 15;
  int t = th >> 4;
  float fr = exp2f(-(float)j * (LOG2_10000 / 32.f));
  float ang = (float)t * fr;
  float sn, cs;
  sincosf(ang, &sn, &cs);
  unsigned short* p = qh + (size_t)t * 3072 + h * 192 + 128 + 2 * j;
  unsigned int v = *(unsigned int*)p;
  float a = bf2f((unsigned short)v), b = bf2f((unsigned short)(v >> 16));
  float na = a * cs - b * sn, nb = a * sn + b * cs;
  *(unsigned int*)p = (unsigned int)f2bf(na) | ((unsigned int)f2bf(nb) << 16);
}

// ---------- LayerNorm(kv) + RoPE(k_pe); f32 in (stride 640), bf16 out ----------
__global__ __launch_bounds__(256) void ln_rope_k(const float* __restrict__ kvfull,
                                                 const float* __restrict__ gamma,
                                                 const float* __restrict__ beta,
                                                 unsigned short* __restrict__ kvln,
                                                 unsigned short* __restrict__ kpe) {
  const int t = blockIdx.x;
  const int tid = threadIdx.x;
  const float* row = kvfull + (size_t)t * 640;
  float x0 = row[tid], x1 = row[tid + 256];
  float sm = x0 + x1;
  float sq = x0 * x0 + x1 * x1;
#pragma unroll
  for (int off = 1; off < 64; off <<= 1) {
    sm += __shfl_xor(sm, off, 64);
    sq += __shfl_xor(sq, off, 64);
  }
  __shared__ float rs[4], rq[4];
  const int lane = tid & 63, wid = tid >> 6;
  if (lane == 0) { rs[wid] = sm; rq[wid] = sq; }
  __syncthreads();
  float tsm = rs[0] + rs[1] + rs[2] + rs[3];
  float tsq = rq[0] + rq[1] + rq[2] + rq[3];
  float mu = tsm * (1.f / 512.f);
  float var = tsq * (1.f / 512.f) - mu * mu;
  float inv = rsqrtf(var + 1e-5f);
  kvln[(size_t)t * 512 + tid]       = f2bf((x0 - mu) * inv * gamma[tid] + beta[tid]);
  kvln[(size_t)t * 512 + tid + 256] = f2bf((x1 - mu) * inv * gamma[tid + 256] + beta[tid + 256]);
  if (tid < 32) {
    float a = row[512 + 2 * tid], b = row[512 + 2 * tid + 1];
    float fr = exp2f(-(float)tid * (LOG2_10000 / 32.f));
    float ang = (float)t * fr;
    float sn, cs;
    sincosf(ang, &sn, &cs);
    kpe[(size_t)t * 64 + 2 * tid]     = f2bf(a * cs - b * sn);
    kpe[(size_t)t * 64 + 2 * tid + 1] = f2bf(a * sn + b * cs);
  }
}

// ---------- V transpose: kvb[t][h*256+128+c] -> Vt[h][c][t] ----------
__global__ __launch_bounds__(256) void transpose_v(const unsigned short* __restrict__ kvb,
                                                   unsigned short* __restrict__ Vt) {
  __shared__ unsigned short tile[64][72];
  const int tb = blockIdx.x * 64;
  const int h  = blockIdx.y >> 1;
  const int c0 = (blockIdx.y & 1) * 64;
  const int tid = threadIdx.x;
  const int r  = tid >> 4;
  const int c4 = (tid & 15) * 4;
#pragma unroll
  for (int rep = 0; rep < 4; ++rep) {
    const int t = rep * 16 + r;
    uint2 d = *(const uint2*)(kvb + (size_t)(tb + t) * 4096 + h * 256 + 128 + c0 + c4);
    *(uint2*)&tile[t][c4] = d;
  }
  __syncthreads();
#pragma unroll
  for (int rep = 0; rep < 4; ++rep) {
    const int c = rep * 16 + r;
    unsigned int lo = (unsigned int)tile[c4 + 0][c] | ((unsigned int)tile[c4 + 1][c] << 16);
    unsigned int hi = (unsigned int)tile[c4 + 2][c] | ((unsigned int)tile[c4 + 3][c] << 16);
    uint2 o; o.x = lo; o.y = hi;
    *(uint2*)(Vt + ((size_t)h * 128 + c0 + c) * 4096 + tb + c4) = o;
  }
}

// ---------- MFMA flash attention v6 ----------
// v3 structure (4 waves x 32 q-rows, K+V staged per tile, 2 barriers) with the
// sK layout changed from 6x[64][32] (64B stride, 8-way conflicts) to
// 3x[64 keys][64 shorts] super-panels (128B stride) with chunk^=(key&7) XOR
// swizzle on BOTH sides: pre-swizzled global source (linear gl_lds dest) +
// swizzled ds_read_b128 — same pattern as the proven conflict-free sVt.
__global__ __launch_bounds__(256, 2) void attn_mfma(const unsigned short* __restrict__ qh,
                                                    const unsigned short* __restrict__ kvb,
                                                    const unsigned short* __restrict__ kpe,
                                                    const unsigned short* __restrict__ Vt,
                                                    unsigned short* __restrict__ attnh) {
  __shared__ unsigned short sK[3 * 4096];     // 24 KB: 3 super-panels [64 keys][64]
  __shared__ unsigned short sVt[128 * 64];    // 16 KB: swizzled (8-blocks ^ row&7)
  __shared__ unsigned short sP[128 * 72];     // 18 KB: [m][k], per-wave row slices

  const int bid = blockIdx.x;
  const int h = bid & 15;
  const int z = bid >> 4;
  const int qt = (z < 16) ? (31 - z) : (z - 16);
  const int q0 = qt * 128;
  const int tid = threadIdx.x;
  const int w = tid >> 6, lane = tid & 63;
  const int quad = lane >> 4, l15 = lane & 15;
  const int wq0 = w * 32;

  const unsigned short* kvbh = kvb + h * 256;
  const unsigned short* Vth = Vt + (size_t)h * 128 * 4096;

  // Q fragments (B-operand: lane l15 = q-row m)
  bf16x8 qF[2][6];
#pragma unroll
  for (int i = 0; i < 2; ++i)
#pragma unroll
    for (int g = 0; g < 6; ++g) {
      const int grow = q0 + wq0 + i * 16 + l15;
      union { uint4 u; bf16x8 v; } tmp;
      tmp.u = *(const uint4*)(qh + (size_t)grow * 3072 + h * 192 + g * 32 + quad * 8);
      qF[i][g] = tmp.v;
    }

  f32x4 oA[2][8];
  float mi[2], li[2];   // per lane: row m = i*16 + l15 (replicated across quads)
#pragma unroll
  for (int i = 0; i < 2; ++i) {
    mi[i] = -1e30f; li[i] = 0.f;
#pragma unroll
    for (int j = 0; j < 8; ++j) { oA[i][j][0] = 0.f; oA[i][j][1] = 0.f; oA[i][j][2] = 0.f; oA[i][j][3] = 0.f; }
  }

  const int nk = 2 * (qt + 1);
  for (int kt = 0; kt < nk; ++kt) {
    const int k0 = kt * 64;
    __syncthreads();   // prev iter: S reads of sK, PV reads of sVt complete

    // ---- stage K: 6 async gl_lds per wave into [sp][key][64] super-panels,
    //      source chunk pre-swizzled (c_src = c ^ (key&7)); LDS dest linear ----
#pragma unroll
    for (int j = 0; j < 6; ++j) {
      const int i = w * 6 + j;
      const int granule = i * 64 + lane;          // [0, 1536)
      const int sp = granule >> 9;                // super-panel 0..2 (64 cols each)
      const int t = granule & 511;
      const int key = t >> 3;
      const int c = t & 7;
      const int c_src = c ^ (key & 7);
      const int col = (sp << 6) + (c_src << 3);   // within [sp*64, sp*64+64)
      const unsigned short* src = (sp < 2)
          ? kvbh + (size_t)(k0 + key) * 4096 + col
          : kpe + (size_t)(k0 + key) * 64 + (col - 128);
      gl_lds16(src, &sK[i * 512]);
    }
    // ---- stage V^T: 4 async gl_lds per wave, XOR-swizzled dest ----
#pragma unroll
    for (int j = 0; j < 4; ++j) {
      const int ii = w * 4 + j;
      const int n = ii * 8 + (lane >> 3);
      const int b = (lane & 7) ^ ((lane >> 3) & 7);
      gl_lds16(Vth + (size_t)n * 4096 + k0 + b * 8, &sVt[ii * 512]);
    }
    __syncthreads();   // staging visible

    // ---- S^T = K Q^T: sc[kk][i], D row = key(quad*4+r), col = m(l15) ----
    f32x4 sc[4][2];
#pragma unroll
    for (int kk = 0; kk < 4; ++kk)
#pragma unroll
      for (int i = 0; i < 2; ++i) { sc[kk][i][0] = 0.f; sc[kk][i][1] = 0.f; sc[kk][i][2] = 0.f; sc[kk][i][3] = 0.f; }
#pragma unroll
    for (int g = 0; g < 6; ++g) {
      const int sp = g >> 1;
      const int cbase = (g & 1) * 4;
      bf16x8 kF[4];
#pragma unroll
      for (int kk = 0; kk < 4; ++kk) {
        const int row = kk * 16 + l15;
        const int cc = (cbase + quad) ^ (l15 & 7);   // row&7 == l15&7
        kF[kk] = *(const bf16x8*)&sK[sp * 4096 + row * 64 + cc * 8];
      }
#pragma unroll
      for (int kk = 0; kk < 4; ++kk)
#pragma unroll
        for (int i = 0; i < 2; ++i)
          sc[kk][i] = mfma16(kF[kk], qF[i][g], sc[kk][i]);
    }

    // ---- online softmax over keys (in-lane 16 + shfl_xor 16,32) ----
    const bool msk = (kt >= 2 * qt);
    float alpha[2];
#pragma unroll
    for (int i = 0; i < 2; ++i) {
      const int grow = q0 + wq0 + i * 16 + l15;
      if (msk) {
#pragma unroll
        for (int kk = 0; kk < 4; ++kk)
#pragma unroll
          for (int rr = 0; rr < 4; ++rr) {
            const int gk = k0 + kk * 16 + quad * 4 + rr;
            if (gk > grow) sc[kk][i][rr] = -1e30f;
          }
      }
      float mx = -1e30f;
#pragma unroll
      for (int kk = 0; kk < 4; ++kk)
#pragma unroll
        for (int rr = 0; rr < 4; ++rr) mx = fmaxf(mx, sc[kk][i][rr]);
      mx = fmaxf(mx, __shfl_xor(mx, 16, 64));
      mx = fmaxf(mx, __shfl_xor(mx, 32, 64));
      const float mnew = fmaxf(mi[i], mx);
      alpha[i] = __builtin_amdgcn_exp2f(mi[i] - mnew);
      float sum = 0.f;
#pragma unroll
      for (int kk = 0; kk < 4; ++kk)
#pragma unroll
        for (int rr = 0; rr < 4; ++rr) {
          const float p = __builtin_amdgcn_exp2f(sc[kk][i][rr] - mnew);
          sc[kk][i][rr] = p;
          sum += p;
        }
      sum += __shfl_xor(sum, 16, 64);
      sum += __shfl_xor(sum, 32, 64);
      li[i] = li[i] * alpha[i] + sum;
      mi[i] = mnew;
    }

    // ---- rescale O (alpha fetched to C-layout rows: 8 shfls) ----
#pragma unroll
    for (int i = 0; i < 2; ++i)
#pragma unroll
      for (int rr = 0; rr < 4; ++rr) {
        const float af = __shfl(alpha[i], (lane & 48) | (quad * 4 + rr), 64);
#pragma unroll
        for (int j = 0; j < 8; ++j) oA[i][j][rr] *= af;
      }

    // ---- pack P (keys consecutive in regs) -> 8 b64 LDS writes ----
#pragma unroll
    for (int kk = 0; kk < 4; ++kk)
#pragma unroll
      for (int i = 0; i < 2; ++i) {
        union { float f; unsigned int u; } p0, p1, p2, p3;
        p0.f = sc[kk][i][0]; p1.f = sc[kk][i][1]; p2.f = sc[kk][i][2]; p3.f = sc[kk][i][3];
        uint2 pk;
        pk.x = (p0.u >> 16) | (p1.u & 0xFFFF0000u);
        pk.y = (p2.u >> 16) | (p3.u & 0xFFFF0000u);
        *(uint2*)&sP[(size_t)(wq0 + i * 16 + l15) * 72 + kk * 16 + quad * 4] = pk;
      }

    // ---- O += P V (own sP rows: no barrier; sVt covered by stage barrier) ----
#pragma unroll
    for (int ks = 0; ks < 2; ++ks) {
      bf16x8 pF[2], vF[8];
#pragma unroll
      for (int i = 0; i < 2; ++i)
        pF[i] = *(const bf16x8*)&sP[(size_t)(wq0 + i * 16 + l15) * 72 + ks * 32 + quad * 8];
#pragma unroll
      for (int j = 0; j < 8; ++j) {
        const int n = j * 16 + l15;
        const int blk = (ks * 4 + quad) ^ (l15 & 7);
        vF[j] = *(const bf16x8*)&sVt[(size_t)n * 64 + blk * 8];
      }
#pragma unroll
      for (int i = 0; i < 2; ++i)
#pragma unroll
        for (int j = 0; j < 8; ++j)
          oA[i][j] = mfma16(pF[i], vF[j], oA[i][j]);
    }
  }

  // ---- epilogue: O / l (l fetched to C-layout rows) ----
  float linv[2];
  linv[0] = 1.f / li[0];
  linv[1] = 1.f / li[1];
#pragma unroll
  for (int i = 0; i < 2; ++i)
#pragma unroll
    for (int rr = 0; rr < 4; ++rr) {
      const float lf = __shfl(linv[i], (lane & 48) | (quad * 4 + rr), 64);
      const size_t grow = (size_t)(q0 + wq0 + i * 16 + quad * 4 + rr);
#pragma unroll
      for (int j = 0; j < 8; ++j)
        attnh[grow * 2048 + h * 128 + j * 16 + l15] = f2bf(oA[i][j][rr] * lf);
    }
}

extern "C" void kernel_launch(void* const* d_in, const int* in_sizes, int n_in,
                              void* d_out, int out_size, void* d_ws, size_t ws_size,
                              hipStream_t stream) {
  const float* x        = (const float*)d_in[0];
  const float* wq       = (const float*)d_in[1];
  const float* wkv_a    = (const float*)d_in[2];
  const float* kv_gamma = (const float*)d_in[3];
  const float* kv_beta  = (const float*)d_in[4];
  const float* wkv_b    = (const float*)d_in[5];
  const float* wo       = (const float*)d_in[6];
  float* out = (float*)d_out;

  char* p = (char*)d_ws;
  unsigned short* xh    = (unsigned short*)p; p += (size_t)4096 * 2048 * 2;  // also Vt (aliased after xh dead)
  unsigned short* wqh   = (unsigned short*)p; p += (size_t)3072 * 2048 * 2;
  unsigned short* wah   = (unsigned short*)p; p += (size_t)640 * 2048 * 2;
  unsigned short* wbh   = (unsigned short*)p; p += (size_t)4096 * 512 * 2;
  unsigned short* woh   = (unsigned short*)p; p += (size_t)2048 * 2048 * 2;
  unsigned short* qh    = (unsigned short*)p; p += (size_t)4096 * 3072 * 2;
  float*          kvful = (float*)p;          p += (size_t)4096 * 640 * 4;
  unsigned short* kvlnh = (unsigned short*)p; p += (size_t)4096 * 512 * 2;
  unsigned short* kpeh  = (unsigned short*)p; p += (size_t)4096 * 64 * 2;
  unsigned short* kvbh  = (unsigned short*)p; p += (size_t)4096 * 4096 * 2;
  unsigned short* attnh = (unsigned short*)p; p += (size_t)4096 * 2048 * 2;
  if ((size_t)(p - (char*)d_ws) > ws_size) return;
  unsigned short* Vt = xh;  // 16 MB alias: xh consumed by gemms 1&3 before transpose_v runs

  cast_bf16<<<8192, 256, 0, stream>>>(x,     xh,  4096 * 2048, 4096 * 2048);
  cast_bf16<<<6144, 256, 0, stream>>>(wq,    wqh, 3072 * 2048, 3072 * 2048);
  cast_bf16<<<1280, 256, 0, stream>>>(wkv_a, wah, 576 * 2048,  640 * 2048);
  cast_bf16<<<2048, 256, 0, stream>>>(wkv_b, wbh, 4096 * 512,  4096 * 512);
  cast_bf16<<<4096, 256, 0, stream>>>(wo,    woh, 2048 * 2048, 2048 * 2048);

  // 1. q = QSCALE * (x @ wq^T) -> bf16 (exp2-domain attention)
  gemm_bf16<true><<<dim3(24, 32), 256, 0, stream>>>(xh, wqh, qh, 4096, 3072, 2048, QSCALE);
  // 2. rope(q_pe) in place
  rope_q_bf<<<8192, 256, 0, stream>>>(qh);
  // 3. kv_full = x @ wkv_a^T -> f32 (LN stats precision), padded N=640
  gemm_bf16<false><<<dim3(5, 32), 256, 0, stream>>>(xh, wah, kvful, 4096, 640, 2048, 1.f);
  // 4. layernorm + rope(k_pe) -> bf16
  ln_rope_k<<<4096, 256, 0, stream>>>(kvful, kv_gamma, kv_beta, kvlnh, kpeh);
  // 5. kvb = kvln @ wkv_b^T -> bf16
  gemm_bf16<true><<<dim3(32, 32), 256, 0, stream>>>(kvlnh, wbh, kvbh, 4096, 4096, 512, 1.f);
  // 5b. V^T for attention (overwrites xh — dead by now)
  transpose_v<<<dim3(64, 32), 256, 0, stream>>>(kvbh, Vt);
  // 6. causal MFMA flash attention (sK super-panel swizzle)
  attn_mfma<<<512, 256, 0, stream>>>(qh, kvbh, kpeh, Vt, attnh);
  // 7. out = attn @ wo^T -> f32
  gemm_bf16<false><<<dim3(16, 32), 256, 0, stream>>>(attnh, woh, out, 4096, 2048, 2048, 1.f);
}